// Round 1
// baseline (2429.112 us; speedup 1.0000x reference)
//
#include <hip/hip_runtime.h>

// Problem: out(N=100000,128) = zeros .at[i1].add(deltas[:, :128]).at[i2].add(deltas[:,128:256])
//          b(E=500000,64)    = deltas[:, 256:320]
// d_in: [0]=unary (unused), [1]=binary (unused), [2]=deltas (E,320) f32,
//       [3]=index1 (E,1) i32, [4]=index2 (E,1) i32
// d_out: out (N*128 f32) ++ b (E*64 f32)

#define N_UNARY 128
#define NB 64
#define DROW_F4 80   // 320 floats / 4

__global__ void scatter_add_copy_kernel(const float4* __restrict__ deltas,
                                        const int* __restrict__ index1,
                                        const int* __restrict__ index2,
                                        float* __restrict__ out,     // N*128 floats
                                        float4* __restrict__ bout,   // E*16 float4
                                        long long total)             // E*80
{
    long long t = (long long)blockIdx.x * blockDim.x + threadIdx.x;
    if (t >= total) return;

    int e = (int)(t / DROW_F4);
    int c = (int)(t % DROW_F4);

    float4 v = deltas[t];

    if (c < 32) {
        // ux -> out[index1[e]]
        int i1 = index1[e];
        float* dst = out + (long long)i1 * N_UNARY + c * 4;
        atomicAdd(dst + 0, v.x);
        atomicAdd(dst + 1, v.y);
        atomicAdd(dst + 2, v.z);
        atomicAdd(dst + 3, v.w);
    } else if (c < 64) {
        // uy -> out[index2[e]]
        int i2 = index2[e];
        float* dst = out + (long long)i2 * N_UNARY + (c - 32) * 4;
        atomicAdd(dst + 0, v.x);
        atomicAdd(dst + 1, v.y);
        atomicAdd(dst + 2, v.z);
        atomicAdd(dst + 3, v.w);
    } else {
        // b copy
        bout[(long long)e * 16 + (c - 64)] = v;
    }
}

extern "C" void kernel_launch(void* const* d_in, const int* in_sizes, int n_in,
                              void* d_out, int out_size, void* d_ws, size_t ws_size,
                              hipStream_t stream) {
    const float4* deltas = (const float4*)d_in[2];
    const int* index1    = (const int*)d_in[3];
    const int* index2    = (const int*)d_in[4];

    const int N = in_sizes[0] / N_UNARY;                 // 100000
    const int E = in_sizes[2] / (2 * N_UNARY + NB);      // 500000

    float*  out  = (float*)d_out;
    float4* bout = (float4*)((float*)d_out + (long long)N * N_UNARY);

    // Zero the scatter-add target region (harness poisons d_out with 0xAA).
    hipMemsetAsync(out, 0, (size_t)N * N_UNARY * sizeof(float), stream);

    long long total = (long long)E * DROW_F4;            // 40,000,000
    int block = 256;
    long long grid = (total + block - 1) / block;
    scatter_add_copy_kernel<<<(int)grid, block, 0, stream>>>(
        deltas, index1, index2, out, bout, total);
}

// Round 2
// 1065.569 us; speedup vs baseline: 2.2796x; 2.2796x over previous
//
#include <hip/hip_runtime.h>

// Problem: out(N=100000,128) = zeros .at[i1].add(deltas[:, :128]).at[i2].add(deltas[:,128:256])
//          b(E=500000,64)    = deltas[:, 256:320]
// Strategy: CSR build (hist + scan + fill) then gather (1 wave per out row, deg~10),
// replacing 128M fp32 atomics (atomic-pipe bound, 75 G/s) with pure coalesced reads.
//
// d_in: [0]=unary (unused), [1]=binary (unused), [2]=deltas (E,320) f32,
//       [3]=index1 (E,) i32, [4]=index2 (E,) i32
// d_out: out (N*128 f32) ++ b (E*64 f32)

#define N_UNARY 128
#define NB 64
#define DROW 320          // floats per deltas row
#define DROW_F4 80

// --- 1. histogram: cnt[idx]++ over both index arrays (items: [0,E)=i1, [E,2E)=i2)
__global__ void hist_kernel(const int* __restrict__ i1, const int* __restrict__ i2,
                            int* __restrict__ cnt, int E) {
    int t = blockIdx.x * blockDim.x + threadIdx.x;
    if (t >= 2 * E) return;
    int idx = (t < E) ? i1[t] : i2[t - E];
    atomicAdd(&cnt[idx], 1);
}

// --- 2a. per-block exclusive scan; block totals to aux
__global__ void scan1_kernel(const int* __restrict__ cnt, int* __restrict__ off,
                             int* __restrict__ aux, int M) {
    __shared__ int tmp[256];
    int t = threadIdx.x;
    int g = blockIdx.x * 256 + t;
    int x = (g < M) ? cnt[g] : 0;
    tmp[t] = x;
    __syncthreads();
    for (int o = 1; o < 256; o <<= 1) {
        int v = (t >= o) ? tmp[t - o] : 0;
        __syncthreads();
        tmp[t] += v;
        __syncthreads();
    }
    if (g < M) off[g] = tmp[t] - x;              // exclusive within block
    if (t == 255) aux[blockIdx.x] = tmp[255];    // block total
}

// --- 2b. exclusive scan of block totals (single block, nb <= 512)
__global__ void scan2_kernel(int* __restrict__ aux, int nb) {
    __shared__ int tmp[512];
    int t = threadIdx.x;
    int x = (t < nb) ? aux[t] : 0;
    tmp[t] = x;
    __syncthreads();
    for (int o = 1; o < 512; o <<= 1) {
        int v = (t >= o) ? tmp[t - o] : 0;
        __syncthreads();
        tmp[t] += v;
        __syncthreads();
    }
    if (t < nb) aux[t] = tmp[t] - x;             // exclusive
}

// --- 2c. add block offsets
__global__ void scan3_kernel(int* __restrict__ off, const int* __restrict__ aux, int M) {
    int g = blockIdx.x * 256 + threadIdx.x;
    if (g < M) off[g] += aux[blockIdx.x];
}

// --- 3. fill item list: list[off[idx] + cursor[idx]++] = item id
__global__ void fill_kernel(const int* __restrict__ i1, const int* __restrict__ i2,
                            const int* __restrict__ off, int* __restrict__ cur,
                            int* __restrict__ list, int E) {
    int t = blockIdx.x * blockDim.x + threadIdx.x;
    if (t >= 2 * E) return;
    int idx = (t < E) ? i1[t] : i2[t - E];
    int pos = off[idx] + atomicAdd(&cur[idx], 1);
    list[pos] = t;
}

// --- 4. gather: one wave per output row; lane holds float2 (128 cols / 64 lanes)
__global__ void gather_kernel(const float* __restrict__ deltas,
                              const int* __restrict__ off, const int* __restrict__ list,
                              float* __restrict__ out, int N, int E) {
    int wave = threadIdx.x >> 6;
    int lane = threadIdx.x & 63;
    int row = blockIdx.x * 4 + wave;
    if (row >= N) return;
    int beg = off[row], end = off[row + 1];
    float2 acc = {0.f, 0.f};
    int p = beg;
    for (; p + 1 < end; p += 2) {              // 2-wide for load ILP
        int s0 = list[p], s1 = list[p + 1];
        long long b0 = (s0 < E) ? (long long)s0 * DROW : (long long)(s0 - E) * DROW + N_UNARY;
        long long b1 = (s1 < E) ? (long long)s1 * DROW : (long long)(s1 - E) * DROW + N_UNARY;
        float2 v0 = *(const float2*)(deltas + b0 + 2 * lane);
        float2 v1 = *(const float2*)(deltas + b1 + 2 * lane);
        acc.x += v0.x + v1.x;
        acc.y += v0.y + v1.y;
    }
    if (p < end) {
        int s0 = list[p];
        long long b0 = (s0 < E) ? (long long)s0 * DROW : (long long)(s0 - E) * DROW + N_UNARY;
        float2 v0 = *(const float2*)(deltas + b0 + 2 * lane);
        acc.x += v0.x;
        acc.y += v0.y;
    }
    *(float2*)(out + (long long)row * N_UNARY + 2 * lane) = acc;
}

// --- 5. b copy: bout[e][j] = deltas4[e*80 + 64 + j]
__global__ void bcopy_kernel(const float4* __restrict__ d4, float4* __restrict__ bout,
                             int total) {
    int t = blockIdx.x * blockDim.x + threadIdx.x;
    if (t >= total) return;
    int e = t >> 4;
    int j = t & 15;
    bout[t] = d4[(long long)e * DROW_F4 + 64 + j];
}

extern "C" void kernel_launch(void* const* d_in, const int* in_sizes, int n_in,
                              void* d_out, int out_size, void* d_ws, size_t ws_size,
                              hipStream_t stream) {
    const float*  deltas = (const float*)d_in[2];
    const int*    index1 = (const int*)d_in[3];
    const int*    index2 = (const int*)d_in[4];

    const int N = in_sizes[0] / N_UNARY;                 // 100000
    const int E = in_sizes[2] / (2 * N_UNARY + NB);      // 500000
    const int S = 2 * E;                                 // scatter items
    const int M = N + 1;                                 // scan length

    float*  out  = (float*)d_out;
    float4* bout = (float4*)((float*)d_out + (long long)N * N_UNARY);

    // workspace layout (ints)
    int* ws   = (int*)d_ws;
    int* cnt  = ws;                 // M
    int* off  = cnt + M;            // M
    int* aux  = off + M;            // 512
    int* cur  = aux + 512;          // N
    int* list = cur + N;            // S
    // total ~ 5.2 MB

    hipMemsetAsync(cnt, 0, (size_t)M * sizeof(int), stream);
    hipMemsetAsync(cur, 0, (size_t)N * sizeof(int), stream);

    int block = 256;

    // histogram
    hist_kernel<<<(S + block - 1) / block, block, 0, stream>>>(index1, index2, cnt, E);

    // exclusive scan cnt -> off  (off[N] = total = S)
    int nb = (M + 255) / 256;       // 391 <= 512
    scan1_kernel<<<nb, 256, 0, stream>>>(cnt, off, aux, M);
    scan2_kernel<<<1, 512, 0, stream>>>(aux, nb);
    scan3_kernel<<<nb, 256, 0, stream>>>(off, aux, M);

    // fill CSR list
    fill_kernel<<<(S + block - 1) / block, block, 0, stream>>>(index1, index2, off, cur, list, E);

    // gather into out (writes every row, incl. zero-degree rows)
    gather_kernel<<<(N + 3) / 4, 256, 0, stream>>>(deltas, off, list, out, N, E);

    // b copy
    int btotal = E * 16;            // float4 count
    bcopy_kernel<<<(btotal + block - 1) / block, block, 0, stream>>>((const float4*)deltas, bout, btotal);
}